// Round 9
// baseline (1079.534 us; speedup 1.0000x reference)
//
#include <hip/hip_runtime.h>
#include <stdint.h>

typedef unsigned short u16;
typedef __attribute__((ext_vector_type(8))) short short8;
typedef __attribute__((ext_vector_type(4))) float f32x4;

#define AS1 __attribute__((address_space(1)))
#define AS3 __attribute__((address_space(3)))

static __device__ __forceinline__ void gload_lds16(const void* g, void* l) {
  __builtin_amdgcn_global_load_lds((const AS1 void*)g, (AS3 void*)l, 16, 0, 0);
}

static __device__ __forceinline__ u16 bf16r(float f) {
  union { float f; uint32_t u; } c; c.f = f;
  uint32_t u = c.u;
  u += 0x7fffu + ((u >> 16) & 1u);
  return (u16)(u >> 16);
}

static constexpr int NB = 16, CIN = 256, COUT = 256, HW = 128, SDIM = 512;
static constexpr float SCALE = 1.0f / 48.0f;   // 1/sqrt(Cin*3*3)

// ---------------- K1: s[b][ci] = style[b,:] @ mod_w[ci,:] + mod_b[ci] ----------------
__global__ void k_style(const float* __restrict__ style, const float* __restrict__ mod_w,
                        const float* __restrict__ mod_b, float* __restrict__ s) {
  int b = blockIdx.x, ci = threadIdx.x;
  const float4* st = (const float4*)(style + (size_t)b * SDIM);
  const float4* mw = (const float4*)(mod_w + (size_t)ci * SDIM);
  float acc = 0.f;
  #pragma unroll 4
  for (int j = 0; j < SDIM / 4; ++j) {
    float4 a = st[j], w = mw[j];
    acc += a.x * w.x + a.y * w.y + a.z * w.z + a.w * w.w;
  }
  s[b * CIN + ci] = acc + mod_b[ci];
}

// ------- K2: modulated+demodulated weights -> bf16, packed in MFMA-fragment order ----
// Apack[b]: frag(KT=kpos*4+ci0, KK, wr, mt) = 512 u16 block; within block lane*8+e,
// lane = (co&15) | (((ci>>3)&3)<<4), e = ci&7. co = wr*128+mt*16+(co&15),
// ci = (KT&3)*64 + KK*32 + (lane>>4)*8 + e.
__global__ void k_wmod(const float* __restrict__ weight, const float* __restrict__ s,
                       u16* __restrict__ Wb) {
  __shared__ float wld[CIN * 9];
  __shared__ float red[8];
  int bid = blockIdx.x;
  int b = bid >> 8, co = bid & 255;
  int t = threadIdx.x;
  const float* wsrc = weight + (size_t)co * (CIN * 9);
  for (int i = t; i < CIN * 9; i += 256) wld[i] = wsrc[i];
  __syncthreads();
  int ci = t;
  float sv = s[b * CIN + ci];
  float v[9];
  float sq = 0.f;
  #pragma unroll
  for (int k = 0; k < 9; ++k) {
    float w = SCALE * wld[ci * 9 + k] * sv;
    v[k] = w;
    sq += w * w;
  }
  #pragma unroll
  for (int off = 32; off; off >>= 1) sq += __shfl_down(sq, off);
  int lane = t & 63, wid = t >> 6;
  if (lane == 0) red[wid] = sq;
  __syncthreads();
  if (t == 0) red[4] = rsqrtf(red[0] + red[1] + red[2] + red[3] + 1e-8f);
  __syncthreads();
  float demod = red[4];
  int KK = (ci >> 5) & 1, seg = (ci >> 3) & 3, e = ci & 7;
  int lane2 = (co & 15) | (seg << 4);
  int wr = co >> 7, mt = (co >> 4) & 7;
  #pragma unroll
  for (int k = 0; k < 9; ++k) {
    int KT = k * 4 + (ci >> 6);
    size_t dst = (size_t)b * 9 * 65536 +
                 ((((size_t)KT * 2 + KK) * 2 + wr) * 8 + mt) * 512 + lane2 * 8 + e;
    Wb[dst] = bf16r(v[k] * demod);
  }
}

// ---------------- K3: x fp32 [b][ci][h][w] -> bf16 transposed padded -----------------
// xTp[b][hh][pxp][ci]: hh in [0,130) = image row h+1 (hh=0 and hh=129 are zero guard
// rows); pxp in [0,130): pxp==0 and pxp==129 are zero pad columns, pxp=1+w.
__global__ void k_xt(const float* __restrict__ x, u16* __restrict__ xTp) {
  __shared__ u16 T[128 * 65];
  int bid = blockIdx.x;
  int b = bid >> 7, h = bid & 127;
  int t = threadIdx.x;
  size_t rowbase = ((size_t)b * 130 + (h + 1)) * 130 * CIN;
  // zero pad columns
  xTp[rowbase + t] = 0;
  xTp[rowbase + (size_t)129 * CIN + t] = 0;
  // zero guard rows
  if (h == 0) {
    uint32_t* g = (uint32_t*)(xTp + (size_t)b * 130 * 130 * CIN);
    for (int i = t; i < 130 * CIN / 2; i += 256) g[i] = 0;
  }
  if (h == 127) {
    uint32_t* g = (uint32_t*)(xTp + ((size_t)b * 130 + 129) * 130 * CIN);
    for (int i = t; i < 130 * CIN / 2; i += 256) g[i] = 0;
  }
  for (int ci0 = 0; ci0 < CIN; ci0 += 64) {
    __syncthreads();
    #pragma unroll
    for (int i = 0; i < 8; ++i) {
      int idx = t + i * 256;
      int ci = idx >> 5, px4 = idx & 31;
      float4 v = *(const float4*)(x + (((size_t)b * CIN + ci0 + ci) * HW + h) * HW + px4 * 4);
      T[(px4 * 4 + 0) * 65 + ci] = bf16r(v.x);
      T[(px4 * 4 + 1) * 65 + ci] = bf16r(v.y);
      T[(px4 * 4 + 2) * 65 + ci] = bf16r(v.z);
      T[(px4 * 4 + 3) * 65 + ci] = bf16r(v.w);
    }
    __syncthreads();
    int ci = t & 63, pxo = t >> 6;
    #pragma unroll
    for (int i = 0; i < 32; ++i) {
      int px = i * 4 + pxo;
      xTp[rowbase + (size_t)(px + 1) * CIN + ci0 + ci] = T[px * 65 + ci];
    }
  }
}

// ------ K4: implicit GEMM conv: A direct (fragment-packed, coalesced), B via LDS ----
// block = (b, hp): out 256co x 256px (rows 2hp,2hp+1). 8 waves 2Mx4N, wave 128x64.
// K = 36 K-tiles of 64 (2 kk-halves each). A frags load straight from packed Wb
// (1KB contiguous per instr, L1/L2-served), 3-array ping-pong rolling window.
// B staged via gload_lds (swizzled, dbuf 2x32KB), raw barrier + counted vmcnt per kt.
static constexpr int BSLOT = 16384;  // u16 per B slot (256 rows x 64)

__global__ __launch_bounds__(512, 2) void k_conv(const u16* __restrict__ Wb,
                                                 const u16* __restrict__ xTp,
                                                 const float* __restrict__ bias,
                                                 float* __restrict__ out) {
  extern __shared__ u16 lds[];
  int bid = blockIdx.x;
  // T1: bijective XCD swizzle (nwg=1024, 1024%8==0)
  int swz = (bid & 7) * 128 + (bid >> 3);
  int b = swz >> 6, hp = swz & 63;
  int h0 = hp * 2;

  int t = threadIdx.x, lane = t & 63, wid = t >> 6;
  int wr = wid >> 2, wc = wid & 3;
  int rowoff = wid * 8 + (lane >> 3);               // staging row within 64-row unit
  int swzc = ((lane & 7) ^ (lane >> 3)) << 3;       // pre-swizzled source col (u16)
  int cxor = (lane & 7) << 3;                       // read-side XOR
  int klo = (lane >> 4) << 3;
  int bro = (wc * 64 + (lane & 15)) * 64;           // + nt*1024
  const u16* Ab = Wb + (size_t)b * 9 * 65536;
  const size_t xB = (size_t)b * 130 * 130 * 256;

  f32x4 acc[8][4];
  #pragma unroll
  for (int i = 0; i < 8; ++i)
    #pragma unroll
    for (int j = 0; j < 4; ++j) acc[i][j] = (f32x4)0.f;

#define LOADA(DST, KT, KK)                                                       \
  do {                                                                           \
    const u16* p_ = Ab + (size_t)((((KT) * 2 + (KK)) * 2 + wr) * 8) * 512        \
                    + lane * 8;                                                  \
    _Pragma("unroll")                                                            \
    for (int mt = 0; mt < 8; ++mt) DST[mt] = *(const short8*)(p_ + mt * 512);    \
  } while (0)

#define STAGEB(KT)                                                               \
  do {                                                                           \
    int kpos_ = (KT) >> 2, ci0_ = ((KT) & 3) << 6;                               \
    int kh_ = kpos_ < 3 ? 0 : (kpos_ < 6 ? 1 : 2);                               \
    int kw_ = kpos_ - kh_ * 3;                                                   \
    u16* d_ = lds + ((KT) & 1) * BSLOT;                                          \
    _Pragma("unroll")                                                            \
    for (int i = 0; i < 4; ++i) {                                                \
      int hh_ = h0 + kh_ + (i >> 1);                                             \
      int pxp_ = kw_ + (i & 1) * 64 + rowoff;                                    \
      const u16* s_ = xTp + xB + ((size_t)hh_ * 130 + pxp_) * 256 + ci0_ + swzc; \
      gload_lds16(s_, d_ + (i * 64 + wid * 8) * 64);                             \
    }                                                                            \
  } while (0)

#define LD4B(S, KK)                                                              \
  do {                                                                           \
    _Pragma("unroll")                                                            \
    for (int nt = 0; nt < 4; ++nt)                                               \
      bf[nt] = *(const short8*)&(S)[bro + nt * 1024 + ((((KK) * 32) + klo) ^ cxor)]; \
  } while (0)

#define MFMA32(AF)                                                               \
  _Pragma("unroll")                                                              \
  for (int mt = 0; mt < 8; ++mt)                                                 \
    _Pragma("unroll")                                                            \
    for (int nt = 0; nt < 4; ++nt)                                               \
      acc[mt][nt] =                                                              \
          __builtin_amdgcn_mfma_f32_16x16x32_bf16(AF[mt], bf[nt], acc[mt][nt], 0, 0, 0);

#define KTBODY(KT, AC, AN)                                                       \
  {                                                                              \
    const u16* S_ = lds + ((KT) & 1) * BSLOT;                                    \
    bool pf_ = (KT) + 1 < 36;                                                    \
    if (pf_) STAGEB((KT) + 1);                                                   \
    LOADA(aZ, (KT), 1);                                                          \
    LD4B(S_, 0);                                                                 \
    __builtin_amdgcn_s_setprio(1);                                               \
    MFMA32(AC);                                                                  \
    __builtin_amdgcn_s_setprio(0);                                               \
    if (pf_) LOADA(AN, (KT) + 1, 0);                                             \
    LD4B(S_, 1);                                                                 \
    __builtin_amdgcn_s_setprio(1);                                               \
    MFMA32(aZ);                                                                  \
    __builtin_amdgcn_s_setprio(0);                                               \
    if (pf_) asm volatile("s_waitcnt vmcnt(16)" ::: "memory");                   \
    asm volatile("" ::: "memory");                                               \
    __builtin_amdgcn_s_barrier();                                                \
    asm volatile("" ::: "memory");                                               \
  }

  short8 aX[8], aY[8], aZ[8], bf[4];
  // prologue: stage B tile0; load A(0,kk0); prove stages landed (8 A-loads younger)
  STAGEB(0);
  LOADA(aX, 0, 0);
  asm volatile("s_waitcnt vmcnt(8)" ::: "memory");
  __builtin_amdgcn_s_barrier();
  asm volatile("" ::: "memory");

  #pragma unroll 1
  for (int kt = 0; kt < 36; kt += 2) {
    KTBODY(kt, aX, aY);
    KTBODY(kt + 1, aY, aX);
  }
#undef LOADA
#undef STAGEB
#undef LD4B
#undef MFMA32
#undef KTBODY

  // -------- epilogue: C write --------
  #pragma unroll
  for (int mt = 0; mt < 8; ++mt) {
    #pragma unroll
    for (int j = 0; j < 4; ++j) {
      int co = wr * 128 + mt * 16 + ((lane >> 4) * 4) + j;
      float bv = bias[co];
      #pragma unroll
      for (int nt = 0; nt < 4; ++nt) {
        int px = wc * 64 + nt * 16 + (lane & 15);
        int h = h0 + (px >> 7), w = px & 127;
        out[(((size_t)b * COUT + co) * HW + h) * HW + w] = acc[mt][nt][j] + bv;
      }
    }
  }
}

extern "C" void kernel_launch(void* const* d_in, const int* in_sizes, int n_in,
                              void* d_out, int out_size, void* d_ws, size_t ws_size,
                              hipStream_t stream) {
  const float* x      = (const float*)d_in[0];
  const float* style  = (const float*)d_in[1];
  const float* weight = (const float*)d_in[2];
  const float* mod_w  = (const float*)d_in[3];
  const float* mod_b  = (const float*)d_in[4];
  const float* bias   = (const float*)d_in[5];
  float* out = (float*)d_out;

  char* ws = (char*)d_ws;
  float* s   = (float*)ws;                                           // 16 KB
  u16* Wb    = (u16*)(ws + 16384);                                   // 18.9 MB (packed)
  u16* xTp   = (u16*)(ws + 16384 + (size_t)NB * 9 * COUT * CIN * 2); // 138.4 MB

  (void)hipFuncSetAttribute((const void*)k_conv,
                            hipFuncAttributeMaxDynamicSharedMemorySize, 2 * BSLOT * 2);

  k_style<<<NB, 256, 0, stream>>>(style, mod_w, mod_b, s);
  k_wmod<<<NB * COUT, 256, 0, stream>>>(weight, s, Wb);
  k_xt<<<NB * HW, 256, 0, stream>>>(x, xTp);
  k_conv<<<NB * (HW / 2), 512, 2 * BSLOT * 2, stream>>>(Wb, xTp, bias, out);
}

// Round 10
// 495.763 us; speedup vs baseline: 2.1775x; 2.1775x over previous
//
#include <hip/hip_runtime.h>
#include <stdint.h>

typedef unsigned short u16;
typedef __attribute__((ext_vector_type(8))) short short8;
typedef __attribute__((ext_vector_type(4))) float f32x4;

#define AS1 __attribute__((address_space(1)))
#define AS3 __attribute__((address_space(3)))

static __device__ __forceinline__ void gload_lds16(const void* g, void* l) {
  __builtin_amdgcn_global_load_lds((const AS1 void*)g, (AS3 void*)l, 16, 0, 0);
}

static __device__ __forceinline__ u16 bf16r(float f) {
  union { float f; uint32_t u; } c; c.f = f;
  uint32_t u = c.u;
  u += 0x7fffu + ((u >> 16) & 1u);
  return (u16)(u >> 16);
}

static constexpr int NB = 16, CIN = 256, COUT = 256, HW = 128, SDIM = 512;
static constexpr float SCALE = 1.0f / 48.0f;   // 1/sqrt(Cin*3*3)

// ---------------- K1: s[b][ci] = style[b,:] @ mod_w[ci,:] + mod_b[ci] ----------------
__global__ void k_style(const float* __restrict__ style, const float* __restrict__ mod_w,
                        const float* __restrict__ mod_b, float* __restrict__ s) {
  int b = blockIdx.x, ci = threadIdx.x;
  const float4* st = (const float4*)(style + (size_t)b * SDIM);
  const float4* mw = (const float4*)(mod_w + (size_t)ci * SDIM);
  float acc = 0.f;
  #pragma unroll 4
  for (int j = 0; j < SDIM / 4; ++j) {
    float4 a = st[j], w = mw[j];
    acc += a.x * w.x + a.y * w.y + a.z * w.z + a.w * w.w;
  }
  s[b * CIN + ci] = acc + mod_b[ci];
}

// ---------------- K2: modulated+demodulated weights -> bf16 Wb[b][kpos][co][ci] ------
__global__ void k_wmod(const float* __restrict__ weight, const float* __restrict__ s,
                       u16* __restrict__ Wb) {
  __shared__ float wld[CIN * 9];
  __shared__ float red[8];
  int bid = blockIdx.x;
  int b = bid >> 8, co = bid & 255;
  int t = threadIdx.x;
  const float* wsrc = weight + (size_t)co * (CIN * 9);
  for (int i = t; i < CIN * 9; i += 256) wld[i] = wsrc[i];
  __syncthreads();
  int ci = t;
  float sv = s[b * CIN + ci];
  float v[9];
  float sq = 0.f;
  #pragma unroll
  for (int k = 0; k < 9; ++k) {
    float w = SCALE * wld[ci * 9 + k] * sv;
    v[k] = w;
    sq += w * w;
  }
  #pragma unroll
  for (int off = 32; off; off >>= 1) sq += __shfl_down(sq, off);
  int lane = t & 63, wid = t >> 6;
  if (lane == 0) red[wid] = sq;
  __syncthreads();
  if (t == 0) red[4] = rsqrtf(red[0] + red[1] + red[2] + red[3] + 1e-8f);
  __syncthreads();
  float demod = red[4];
  #pragma unroll
  for (int k = 0; k < 9; ++k) {
    Wb[(((size_t)b * 9 + k) * COUT + co) * CIN + ci] = bf16r(v[k] * demod);
  }
}

// ---------------- K3: x fp32 [b][ci][h][w] -> bf16 transposed padded -----------------
// xTp[b][hh][pxp][ci]: hh in [0,130) = image row h+1 (hh=0 and hh=129 are zero guard
// rows); pxp in [0,130): pxp==0 and pxp==129 are zero pad columns, pxp=1+w.
__global__ void k_xt(const float* __restrict__ x, u16* __restrict__ xTp) {
  __shared__ u16 T[128 * 65];
  int bid = blockIdx.x;
  int b = bid >> 7, h = bid & 127;
  int t = threadIdx.x;
  size_t rowbase = ((size_t)b * 130 + (h + 1)) * 130 * CIN;
  // zero pad columns
  xTp[rowbase + t] = 0;
  xTp[rowbase + (size_t)129 * CIN + t] = 0;
  // zero guard rows
  if (h == 0) {
    uint32_t* g = (uint32_t*)(xTp + (size_t)b * 130 * 130 * CIN);
    for (int i = t; i < 130 * CIN / 2; i += 256) g[i] = 0;
  }
  if (h == 127) {
    uint32_t* g = (uint32_t*)(xTp + ((size_t)b * 130 + 129) * 130 * CIN);
    for (int i = t; i < 130 * CIN / 2; i += 256) g[i] = 0;
  }
  for (int ci0 = 0; ci0 < CIN; ci0 += 64) {
    __syncthreads();
    #pragma unroll
    for (int i = 0; i < 8; ++i) {
      int idx = t + i * 256;
      int ci = idx >> 5, px4 = idx & 31;
      float4 v = *(const float4*)(x + (((size_t)b * CIN + ci0 + ci) * HW + h) * HW + px4 * 4);
      T[(px4 * 4 + 0) * 65 + ci] = bf16r(v.x);
      T[(px4 * 4 + 1) * 65 + ci] = bf16r(v.y);
      T[(px4 * 4 + 2) * 65 + ci] = bf16r(v.z);
      T[(px4 * 4 + 3) * 65 + ci] = bf16r(v.w);
    }
    __syncthreads();
    int ci = t & 63, pxo = t >> 6;
    #pragma unroll
    for (int i = 0; i < 32; ++i) {
      int px = i * 4 + pxo;
      xTp[rowbase + (size_t)(px + 1) * CIN + ci0 + ci] = T[px * 65 + ci];
    }
  }
}

// -------- K4: implicit GEMM conv, 2 blocks/CU for cross-block pipe overlap ----------
// block = 256 thr (4 waves), tile 128co x 256px (rows 2hp,2hp+1), wave 128x64.
// K = 2304 = 72 K-tiles of 32. LDS dbuf 2 x 24KB (A 128x32 + B 256x32) = 48KB
// -> 2 blocks/CU (96KB LDS, ~210 VGPR): independent barrier domains desync, so one
// block's MFMA cluster fills the other's ds-read/drain interval.
// Swizzle (64B rows): LDS(row, qd) holds source quarter qd^((row>>1)&3); reads apply
// the same XOR -> exactly 2 lanes/bank-group (free).
static constexpr int SLOT = 12288;  // u16 per slot: A 4096 + B 8192

__global__ __launch_bounds__(256, 2) void k_conv(const u16* __restrict__ Wb,
                                                 const u16* __restrict__ xTp,
                                                 const float* __restrict__ bias,
                                                 float* __restrict__ out) {
  extern __shared__ u16 lds[];
  int bid = blockIdx.x;
  // T1: bijective XCD swizzle (nwg=2048, 2048%8==0); same-b, same-co-half adjacency
  int swz = (bid & 7) * 256 + (bid >> 3);
  int b = swz >> 7, r = swz & 127;
  int c2 = r >> 6, hp = r & 63;
  int h0 = hp * 2, co0 = c2 * 128;

  int t = threadIdx.x, lane = t & 63, wid = t >> 6;
  int wc = wid;                                  // 4 waves over px quarters
  int l15 = lane & 15;
  int row0 = wid * 16 + (lane >> 2);             // staging row base
  int sq8 = ((lane & 3) ^ ((lane >> 3) & 3)) << 3;         // pre-swizzled src quarter
  int aswz = (((lane >> 4) ^ ((l15 >> 1) & 3))) << 3;      // read-side quarter
  const u16* Ab = Wb + (size_t)b * 9 * 65536;
  const u16* Bx = xTp + (size_t)b * 130 * 130 * 256;

  f32x4 acc[8][4];
  #pragma unroll
  for (int i = 0; i < 8; ++i)
    #pragma unroll
    for (int j = 0; j < 4; ++j) acc[i][j] = (f32x4)0.f;

#define STAGE(KT, SN)                                                            \
  do {                                                                           \
    int kpos_ = (KT) >> 3, ci0_ = ((KT) & 7) << 5;                               \
    int kh_ = kpos_ < 3 ? 0 : (kpos_ < 6 ? 1 : 2);                               \
    int kw_ = kpos_ - kh_ * 3;                                                   \
    const u16* As_ = Ab + (size_t)kpos_ * 65536 +                                \
                     (size_t)(co0 + row0) * 256 + ci0_ + sq8;                    \
    gload_lds16(As_,         (SN) + wid * 512 + lane * 8);                       \
    gload_lds16(As_ + 16384, (SN) + 2048 + wid * 512 + lane * 8);                \
    _Pragma("unroll")                                                            \
    for (int i_ = 0; i_ < 4; ++i_) {                                             \
      int r_ = i_ * 64 + row0;                                                   \
      const u16* Bs_ = Bx + ((size_t)(h0 + kh_ + (r_ >> 7)) * 130 + kw_          \
                             + (r_ & 127)) * 256 + ci0_ + sq8;                   \
      gload_lds16(Bs_, (SN) + 4096 + i_ * 2048 + wid * 512 + lane * 8);          \
    }                                                                            \
  } while (0)

#define KTBODY(KT, SCUR, SNXT)                                                   \
  {                                                                              \
    if ((KT) + 1 < 72) STAGE((KT) + 1, SNXT);                                    \
    short8 af_[8], bf_[4];                                                       \
    _Pragma("unroll")                                                            \
    for (int mt = 0; mt < 8; ++mt)                                               \
      af_[mt] = *(const short8*)&(SCUR)[mt * 512 + l15 * 32 + aswz];             \
    _Pragma("unroll")                                                            \
    for (int nt = 0; nt < 4; ++nt)                                               \
      bf_[nt] = *(const short8*)&(SCUR)[4096 + wc * 2048 + nt * 512              \
                                        + l15 * 32 + aswz];                      \
    __builtin_amdgcn_s_setprio(1);                                               \
    _Pragma("unroll")                                                            \
    for (int mt = 0; mt < 8; ++mt)                                               \
      _Pragma("unroll")                                                          \
      for (int nt = 0; nt < 4; ++nt)                                             \
        acc[mt][nt] = __builtin_amdgcn_mfma_f32_16x16x32_bf16(af_[mt], bf_[nt],  \
                                                              acc[mt][nt], 0, 0, 0); \
    __builtin_amdgcn_s_setprio(0);                                               \
    __syncthreads();                                                             \
  }

  u16* S0 = lds;
  u16* S1 = lds + SLOT;
  // prologue: stage kt=0 into slot0; __syncthreads drains vmcnt + publishes
  STAGE(0, S0);
  __syncthreads();

  #pragma unroll 1
  for (int kt = 0; kt < 72; kt += 2) {
    KTBODY(kt, S0, S1);
    KTBODY(kt + 1, S1, S0);
  }
#undef STAGE
#undef KTBODY

  // -------- epilogue: C write --------
  #pragma unroll
  for (int mt = 0; mt < 8; ++mt) {
    #pragma unroll
    for (int j = 0; j < 4; ++j) {
      int co = co0 + mt * 16 + ((lane >> 4) * 4) + j;
      float bv = bias[co];
      #pragma unroll
      for (int nt = 0; nt < 4; ++nt) {
        int px = wc * 64 + nt * 16 + l15;
        int h = h0 + (px >> 7), w = px & 127;
        out[(((size_t)b * COUT + co) * HW + h) * HW + w] = acc[mt][nt][j] + bv;
      }
    }
  }
}

extern "C" void kernel_launch(void* const* d_in, const int* in_sizes, int n_in,
                              void* d_out, int out_size, void* d_ws, size_t ws_size,
                              hipStream_t stream) {
  const float* x      = (const float*)d_in[0];
  const float* style  = (const float*)d_in[1];
  const float* weight = (const float*)d_in[2];
  const float* mod_w  = (const float*)d_in[3];
  const float* mod_b  = (const float*)d_in[4];
  const float* bias   = (const float*)d_in[5];
  float* out = (float*)d_out;

  char* ws = (char*)d_ws;
  float* s   = (float*)ws;                                           // 16 KB
  u16* Wb    = (u16*)(ws + 16384);                                   // 18.9 MB
  u16* xTp   = (u16*)(ws + 16384 + (size_t)NB * 9 * COUT * CIN * 2); // 138.4 MB

  k_style<<<NB, 256, 0, stream>>>(style, mod_w, mod_b, s);
  k_wmod<<<NB * COUT, 256, 0, stream>>>(weight, s, Wb);
  k_xt<<<NB * HW, 256, 0, stream>>>(x, xTp);
  k_conv<<<NB * 2 * (HW / 2), 256, 2 * SLOT * 2, stream>>>(Wb, xTp, bias, out);
}

// Round 11
// 444.253 us; speedup vs baseline: 2.4300x; 1.1159x over previous
//
#include <hip/hip_runtime.h>
#include <stdint.h>

typedef unsigned short u16;
typedef __attribute__((ext_vector_type(8))) short short8;
typedef __attribute__((ext_vector_type(4))) float f32x4;

#define AS1 __attribute__((address_space(1)))
#define AS3 __attribute__((address_space(3)))

static __device__ __forceinline__ void gload_lds16(const void* g, void* l) {
  __builtin_amdgcn_global_load_lds((const AS1 void*)g, (AS3 void*)l, 16, 0, 0);
}

static __device__ __forceinline__ u16 bf16r(float f) {
  union { float f; uint32_t u; } c; c.f = f;
  uint32_t u = c.u;
  u += 0x7fffu + ((u >> 16) & 1u);
  return (u16)(u >> 16);
}

static constexpr int NB = 16, CIN = 256, COUT = 256, HW = 128, SDIM = 512;
static constexpr float SCALE = 1.0f / 48.0f;   // 1/sqrt(Cin*3*3)

// ---------------- K1: s[b][ci] = style[b,:] @ mod_w[ci,:] + mod_b[ci] ----------------
__global__ void k_style(const float* __restrict__ style, const float* __restrict__ mod_w,
                        const float* __restrict__ mod_b, float* __restrict__ s) {
  int b = blockIdx.x, ci = threadIdx.x;
  const float4* st = (const float4*)(style + (size_t)b * SDIM);
  const float4* mw = (const float4*)(mod_w + (size_t)ci * SDIM);
  float acc = 0.f;
  #pragma unroll 4
  for (int j = 0; j < SDIM / 4; ++j) {
    float4 a = st[j], w = mw[j];
    acc += a.x * w.x + a.y * w.y + a.z * w.z + a.w * w.w;
  }
  s[b * CIN + ci] = acc + mod_b[ci];
}

// ---------------- K2: modulated+demodulated weights -> bf16 Wb[b][kpos][co][ci] ------
__global__ void k_wmod(const float* __restrict__ weight, const float* __restrict__ s,
                       u16* __restrict__ Wb) {
  __shared__ float wld[CIN * 9];
  __shared__ float red[8];
  int bid = blockIdx.x;
  int b = bid >> 8, co = bid & 255;
  int t = threadIdx.x;
  const float* wsrc = weight + (size_t)co * (CIN * 9);
  for (int i = t; i < CIN * 9; i += 256) wld[i] = wsrc[i];
  __syncthreads();
  int ci = t;
  float sv = s[b * CIN + ci];
  float v[9];
  float sq = 0.f;
  #pragma unroll
  for (int k = 0; k < 9; ++k) {
    float w = SCALE * wld[ci * 9 + k] * sv;
    v[k] = w;
    sq += w * w;
  }
  #pragma unroll
  for (int off = 32; off; off >>= 1) sq += __shfl_down(sq, off);
  int lane = t & 63, wid = t >> 6;
  if (lane == 0) red[wid] = sq;
  __syncthreads();
  if (t == 0) red[4] = rsqrtf(red[0] + red[1] + red[2] + red[3] + 1e-8f);
  __syncthreads();
  float demod = red[4];
  #pragma unroll
  for (int k = 0; k < 9; ++k) {
    Wb[(((size_t)b * 9 + k) * COUT + co) * CIN + ci] = bf16r(v[k] * demod);
  }
}

// ---------------- K3: x fp32 [b][ci][h][w] -> bf16 transposed padded -----------------
// xTp[b][hh][pxp][ci]: hh in [0,130) = image row h+1 (hh=0 and hh=129 are zero guard
// rows); pxp in [0,130): pxp==0 and pxp==129 are zero pad columns, pxp=1+w.
__global__ void k_xt(const float* __restrict__ x, u16* __restrict__ xTp) {
  __shared__ u16 T[128 * 65];
  int bid = blockIdx.x;
  int b = bid >> 7, h = bid & 127;
  int t = threadIdx.x;
  size_t rowbase = ((size_t)b * 130 + (h + 1)) * 130 * CIN;
  // zero pad columns
  xTp[rowbase + t] = 0;
  xTp[rowbase + (size_t)129 * CIN + t] = 0;
  // zero guard rows
  if (h == 0) {
    uint32_t* g = (uint32_t*)(xTp + (size_t)b * 130 * 130 * CIN);
    for (int i = t; i < 130 * CIN / 2; i += 256) g[i] = 0;
  }
  if (h == 127) {
    uint32_t* g = (uint32_t*)(xTp + ((size_t)b * 130 + 129) * 130 * CIN);
    for (int i = t; i < 130 * CIN / 2; i += 256) g[i] = 0;
  }
  int c8 = t & 7, pxb = t >> 3;
  for (int ci0 = 0; ci0 < CIN; ci0 += 64) {
    __syncthreads();
    #pragma unroll
    for (int i = 0; i < 8; ++i) {
      int idx = t + i * 256;
      int ci = idx >> 5, px4 = idx & 31;
      float4 v = *(const float4*)(x + (((size_t)b * CIN + ci0 + ci) * HW + h) * HW + px4 * 4);
      T[(px4 * 4 + 0) * 65 + ci] = bf16r(v.x);
      T[(px4 * 4 + 1) * 65 + ci] = bf16r(v.y);
      T[(px4 * 4 + 2) * 65 + ci] = bf16r(v.z);
      T[(px4 * 4 + 3) * 65 + ci] = bf16r(v.w);
    }
    __syncthreads();
    // vectorized write-out: each thread gathers 8 u16 from T, stores one short8
    #pragma unroll
    for (int i = 0; i < 4; ++i) {
      int px = i * 32 + pxb;
      short8 v;
      #pragma unroll
      for (int j = 0; j < 8; ++j) v[j] = (short)T[px * 65 + c8 * 8 + j];
      *(short8*)&xTp[rowbase + (size_t)(px + 1) * CIN + ci0 + c8 * 8] = v;
    }
  }
}

// -------- K4: implicit GEMM conv, co-major tile, 2 blocks/CU cross-block overlap ----
// block = 256 thr (4 waves 2Mx2N), tile 256co x 128px (one h-row), wave 128x64.
// K = 2304 = 72 K-tiles of 32 (kpos = kt>>3, ci0 = (kt&7)*32). LDS dbuf 2 x 24KB
// (A[256][32] + B[128][32]) = 48KB -> 2 blocks/CU: independent barrier domains, one
// block's MFMA fills the other's stage/drain/ds-read interval. B is block-private
// (3 guard rows, reused within lifetime -> L2-trivial); A = Wb[b] read once/block.
// Swizzle (64B rows, quarters of 16B): LDS quarter q holds src quarter q^((row>>1)&3);
// reads apply same XOR -> dense 1KB per b128 wave-read, 0 conflicts (R10-verified).
static constexpr int SLOT = 12288;  // u16 per slot: A 8192 + B 4096

__global__ __launch_bounds__(256, 2) void k_conv(const u16* __restrict__ Wb,
                                                 const u16* __restrict__ xTp,
                                                 const float* __restrict__ bias,
                                                 float* __restrict__ out) {
  extern __shared__ u16 lds[];
  int bid = blockIdx.x;
  // T1: bijective XCD swizzle (nwg=2048, 2048%8==0); adjacent hp stay adjacent
  int swz = (bid & 7) * 256 + (bid >> 3);
  int b = swz >> 7, h0 = swz & 127;

  int t = threadIdx.x, lane = t & 63, wid = t >> 6;
  int wr = wid >> 1, wc = wid & 1;
  int l15 = lane & 15, seg = lane >> 4;
  int xq = ((seg ^ ((l15 >> 1) & 3))) << 3;            // read-side quarter XOR (u16)
  int ssrc8 = ((lane & 3) ^ ((lane >> 3) & 3)) << 3;   // pre-swizzled src quarter
  const u16* Ab = Wb + (size_t)b * 9 * 65536;
  const u16* Bx = xTp + (size_t)b * 130 * 130 * 256;

  f32x4 acc[8][4];
  #pragma unroll
  for (int i = 0; i < 8; ++i)
    #pragma unroll
    for (int j = 0; j < 4; ++j) acc[i][j] = (f32x4)0.f;

#define STAGE(KT, SN)                                                            \
  do {                                                                           \
    int kpos_ = (KT) >> 3, ci0_ = ((KT) & 7) << 5;                               \
    int kh_ = kpos_ < 3 ? 0 : (kpos_ < 6 ? 1 : 2);                               \
    int kw_ = kpos_ - kh_ * 3;                                                   \
    const u16* As_ = Ab + (size_t)kpos_ * 65536 + ci0_ + ssrc8;                  \
    _Pragma("unroll")                                                            \
    for (int i_ = 0; i_ < 4; ++i_) {                                             \
      int row_ = (wid * 4 + i_) * 16 + (lane >> 2);                              \
      gload_lds16(As_ + (size_t)row_ * 256, (SN) + (wid * 4 + i_) * 512 + lane * 8); \
    }                                                                            \
    const u16* Bs_ = Bx + ((size_t)(h0 + kh_) * 130 + kw_) * 256 + ci0_ + ssrc8; \
    _Pragma("unroll")                                                            \
    for (int i_ = 0; i_ < 2; ++i_) {                                             \
      int r_ = (wid * 2 + i_) * 16 + (lane >> 2);                                \
      gload_lds16(Bs_ + (size_t)r_ * 256,                                        \
                  (SN) + 8192 + (wid * 2 + i_) * 512 + lane * 8);                \
    }                                                                            \
  } while (0)

#define KTBODY(KT, SCUR, SNXT)                                                   \
  {                                                                              \
    if ((KT) + 1 < 72) STAGE((KT) + 1, SNXT);                                    \
    short8 af_[8], bf_[4];                                                       \
    _Pragma("unroll")                                                            \
    for (int mt = 0; mt < 8; ++mt)                                               \
      af_[mt] = *(const short8*)&(SCUR)[(wr * 8 + mt) * 512 + l15 * 32 + xq];    \
    _Pragma("unroll")                                                            \
    for (int nt = 0; nt < 4; ++nt)                                               \
      bf_[nt] = *(const short8*)&(SCUR)[8192 + (wc * 4 + nt) * 512               \
                                        + l15 * 32 + xq];                        \
    __builtin_amdgcn_s_setprio(1);                                               \
    _Pragma("unroll")                                                            \
    for (int mt = 0; mt < 8; ++mt)                                               \
      _Pragma("unroll")                                                          \
      for (int nt = 0; nt < 4; ++nt)                                             \
        acc[mt][nt] = __builtin_amdgcn_mfma_f32_16x16x32_bf16(af_[mt], bf_[nt],  \
                                                              acc[mt][nt], 0, 0, 0); \
    __builtin_amdgcn_s_setprio(0);                                               \
    __syncthreads();                                                             \
  }

  u16* S0 = lds;
  u16* S1 = lds + SLOT;
  STAGE(0, S0);
  __syncthreads();

  #pragma unroll 1
  for (int kt = 0; kt < 72; kt += 2) {
    KTBODY(kt, S0, S1);
    KTBODY(kt + 1, S1, S0);
  }
#undef STAGE
#undef KTBODY

  // -------- epilogue: C write --------
  #pragma unroll
  for (int mt = 0; mt < 8; ++mt) {
    #pragma unroll
    for (int j = 0; j < 4; ++j) {
      int co = wr * 128 + mt * 16 + seg * 4 + j;
      float bv = bias[co];
      #pragma unroll
      for (int nt = 0; nt < 4; ++nt) {
        int px = wc * 64 + nt * 16 + l15;
        out[(((size_t)b * COUT + co) * HW + h0) * HW + px] = acc[mt][nt][j] + bv;
      }
    }
  }
}

extern "C" void kernel_launch(void* const* d_in, const int* in_sizes, int n_in,
                              void* d_out, int out_size, void* d_ws, size_t ws_size,
                              hipStream_t stream) {
  const float* x      = (const float*)d_in[0];
  const float* style  = (const float*)d_in[1];
  const float* weight = (const float*)d_in[2];
  const float* mod_w  = (const float*)d_in[3];
  const float* mod_b  = (const float*)d_in[4];
  const float* bias   = (const float*)d_in[5];
  float* out = (float*)d_out;

  char* ws = (char*)d_ws;
  float* s   = (float*)ws;                                           // 16 KB
  u16* Wb    = (u16*)(ws + 16384);                                   // 18.9 MB
  u16* xTp   = (u16*)(ws + 16384 + (size_t)NB * 9 * COUT * CIN * 2); // 138.4 MB

  (void)hipFuncSetAttribute((const void*)k_conv,
                            hipFuncAttributeMaxDynamicSharedMemorySize, 2 * SLOT * 2);

  k_style<<<NB, 256, 0, stream>>>(style, mod_w, mod_b, s);
  k_wmod<<<NB * COUT, 256, 0, stream>>>(weight, s, Wb);
  k_xt<<<NB * HW, 256, 0, stream>>>(x, xTp);
  k_conv<<<NB * HW, 256, 2 * SLOT * 2, stream>>>(Wb, xTp, bias, out);
}